// Round 16
// baseline (236.535 us; speedup 1.0000x reference)
//
#include <hip/hip_runtime.h>
#include <hip/hip_bf16.h>

// ---------------------------------------------------------------------------
// GCNWithSelfAttention: GCNConv -> MHA(8 heads) -> ReLU -> Linear
// B=4, N=2048, Din=256, H=512, nh=8, dh=64, E=65536, Dout=256.
// Flash v14 = v11 + K-tile 256 (halves barrier drains 32->16; LDS bytes and
// compute structure unchanged; 68 KB -> still 2 blocks/CU). GEMMs: BK=64 +
// T2 both-sides XOR swizzle (validated r15: total 235->229.8).
// ---------------------------------------------------------------------------

#define NN 2048
#define HH 512
#define NHEAD 8
#define DH 64

typedef _Float16 f16;
typedef __attribute__((ext_vector_type(2))) _Float16 f16x2;
typedef __attribute__((ext_vector_type(4))) _Float16 f16x4;
typedef __attribute__((ext_vector_type(8))) _Float16 f16x8;
typedef __attribute__((ext_vector_type(4))) float f32x4;

#define GLOAD_LDS16(g, l)                                              \
  __builtin_amdgcn_global_load_lds(                                    \
      (const __attribute__((address_space(1))) void*)(g),              \
      (__attribute__((address_space(3))) void*)(l), 16, 0, 0)

__device__ __forceinline__ float fast_exp2(float x) {
#if __has_builtin(__builtin_amdgcn_exp2f)
  return __builtin_amdgcn_exp2f(x);
#else
  return exp2f(x);
#endif
}

__device__ __forceinline__ f16x2 cvt_pk_f16(float a, float b) {
#if __has_builtin(__builtin_amdgcn_cvt_pkrtz)
  return __builtin_bit_cast(f16x2, __builtin_amdgcn_cvt_pkrtz(a, b));
#else
  f16x2 r = { (f16)a, (f16)b };
  return r;
#endif
}

// ---------------- fused prep: converts + transposes + deg/cursor init ------

__global__ __launch_bounds__(256) void prep_all_kernel(const float* __restrict__ wi,
                                                       const float* __restrict__ wo,
                                                       const float* __restrict__ wg,
                                                       const float* __restrict__ fcw,
                                                       f16* __restrict__ wi16,
                                                       f16* __restrict__ wo16,
                                                       f16* __restrict__ wg16t,
                                                       f16* __restrict__ fcw16t,
                                                       float* __restrict__ deg,
                                                       int* __restrict__ cursor) {
  __shared__ float tbuf[32][33];
  const int bid = blockIdx.x, t = threadIdx.x;
  if (bid < 768) {                       // wi: 1536*512 f32 = 196608 float4
    const int i = bid * 256 + t;
    const float4 v = ((const float4*)wi)[i];
    f16x4 o = { (f16)v.x, (f16)v.y, (f16)v.z, (f16)v.w };
    ((f16x4*)wi16)[i] = o;
  } else if (bid < 1024) {               // wo: 512*512 f32 = 65536 float4
    const int i = (bid - 768) * 256 + t;
    const float4 v = ((const float4*)wo)[i];
    f16x4 o = { (f16)v.x, (f16)v.y, (f16)v.z, (f16)v.w };
    ((f16x4*)wo16)[i] = o;
  } else if (bid == 1024) {              // deg/cursor init (count_deg adds)
    for (int i = t; i < NN; i += 256) { deg[i] = 0.0f; cursor[i] = 0; }
  } else {                               // transpose-converts
    const int id = bid - 1025;
    const float* in;
    f16* outp;
    int R, C, bx, by;
    if (id < 128) { in = wg;  outp = wg16t;  R = 256; C = 512;
                    bx = id & 15; by = id >> 4; }
    else { int id2 = id - 128; in = fcw; outp = fcw16t; R = 512; C = 256;
           bx = id2 & 7; by = id2 >> 3; }
    const int c0 = bx * 32, r0 = by * 32;
    const int tx = t & 31, ty = t >> 5;
#pragma unroll
    for (int i = 0; i < 32; i += 8) tbuf[ty + i][tx] = in[(size_t)(r0 + ty + i) * C + c0 + tx];
    __syncthreads();
#pragma unroll
    for (int i = 0; i < 32; i += 8)
      outp[(size_t)(c0 + ty + i) * R + r0 + tx] = (f16)tbuf[tx][ty + i];
  }
}

// ---------------- degree / CSR build ----------------

__global__ __launch_bounds__(256) void count_deg_kernel(const int* __restrict__ ei, int E,
                                                        float* __restrict__ deg) {
  int e = blockIdx.x * 256 + threadIdx.x;
  if (e < E) atomicAdd(&deg[ei[E + e]], 1.0f);  // dst row
}

__global__ __launch_bounds__(1024) void build_rowptr_kernel(const float* __restrict__ deg,
                                                            float* __restrict__ dinv,
                                                            int* __restrict__ rowptr) {
  __shared__ int a[NN];
  __shared__ int bbuf[NN];
  const int t = threadIdx.x;
  for (int i = t; i < NN; i += 1024) {
    float dg = deg[i];               // edge count (self-loop NOT included)
    a[i] = (int)dg;
    dinv[i] = rsqrtf(dg + 1.0f);     // degree incl. self-loop
  }
  __syncthreads();
  int* src = a;
  int* dst = bbuf;
  for (int off = 1; off < NN; off <<= 1) {
    for (int i = t; i < NN; i += 1024) {
      int v = src[i];
      if (i >= off) v += src[i - off];
      dst[i] = v;
    }
    __syncthreads();
    int* tmp = src; src = dst; dst = tmp;
  }
  for (int i = t; i < NN; i += 1024) rowptr[i + 1] = src[i];
  if (t == 0) rowptr[0] = 0;
}

__global__ __launch_bounds__(256) void fill_csr_kernel(const int* __restrict__ ei, int E,
                                                       const int* __restrict__ rowptr,
                                                       int* __restrict__ cursor,
                                                       int* __restrict__ csr_src) {
  int e = blockIdx.x * 256 + threadIdx.x;
  if (e < E) {
    int s = ei[e];
    int d = ei[E + e];
    int pos = atomicAdd(&cursor[d], 1);
    csr_src[rowptr[d] + pos] = s;
  }
}

// ---------------- f16 MFMA GEMM: C[M,N] = A[M,K] * Bt[N,K]^T (+bias)(+relu) -
// MTxN128 tile, BK=64, 256 thr = 4 waves; MT=128: wave=64x64 (4x4 mfma),
// MT=64: wave=32x64 (2x4). OUTMODE: 0 f32 [M,N]; 1 f16 [M,N]; 2 qkv split.
// AF32: A is f32, converted during staging.
// LDS XOR swizzle (T2, both-sides): 16B chunk c of row r stored at c^(r&7);
// staging pre-swizzles the GLOBAL source col so global_load_lds dest stays
// linear (rule 21); fragment reads apply the same XOR -> conflict-free.

template <int OUTMODE, bool BIAS, bool RELU, bool AF32, int MT = 128>
__global__ __launch_bounds__(256) void mfma_gemm_kernel(
    const void* __restrict__ Ap, const f16* __restrict__ Bt,
    const float* __restrict__ bias, void* __restrict__ Cout,
    int M, int N, int K,
    f16* __restrict__ q_out, f16* __restrict__ k_out, f16* __restrict__ v_out) {
  constexpr int MI = MT / 32;  // 16-row blocks per wave in M
  constexpr int BK = 64;
  __shared__ f16 As[MT * BK];   // 16 KB (MT=128) / 8 KB (MT=64)
  __shared__ f16 Bs[128 * BK];  // 16 KB
  const int tid = threadIdx.x;
  const int wave = tid >> 6, lane = tid & 63;
  const int quad = lane >> 4, l16 = lane & 15;
  const int m0 = blockIdx.y * MT, n0 = blockIdx.x * 128;
  const int moff = (wave >> 1) * (MI * 16), noff = (wave & 1) * 64;

  f32x4 acc[MI][4];
#pragma unroll
  for (int i = 0; i < MI; ++i)
#pragma unroll
    for (int j = 0; j < 4; ++j) acc[i][j] = (f32x4){0.f, 0.f, 0.f, 0.f};

  const int rpw = MT / 4;       // A rows staged per wave
  const int srow8 = lane >> 3;  // row within an 8-row staging group
  // pre-swizzled global col chunk: LDS chunk (lane&7) holds global chunk
  // (lane&7)^(row&7); row&7 == srow8 for every staging group.
  const int kchsw = (((lane & 7) ^ srow8) * 8);
  const f16* Ag = (const f16*)Ap + (size_t)(m0 + rpw * wave + srow8) * K + kchsw;
  const float* Ag32 = (const float*)Ap + (size_t)(m0 + rpw * wave + srow8) * K + kchsw;
  const f16* Bg = Bt + (size_t)(n0 + 32 * wave + srow8) * K + kchsw;
  f16* As_w = &As[(rpw * wave) * BK];
  f16* Bs_w = &Bs[(32 * wave) * BK];

  for (int k0 = 0; k0 < K; k0 += BK) {
    __syncthreads();
    if (AF32) {
#pragma unroll
      for (int i = 0; i < rpw / 8; ++i) {
        const float* g = Ag32 + k0 + (size_t)(8 * i) * K;
        const float4 u0 = *(const float4*)g;
        const float4 u1 = *(const float4*)(g + 4);
        f16x8 o = { (f16)u0.x, (f16)u0.y, (f16)u0.z, (f16)u0.w,
                    (f16)u1.x, (f16)u1.y, (f16)u1.z, (f16)u1.w };
        *(f16x8*)&As[(rpw * wave + 8 * i + srow8) * BK + (lane & 7) * 8] = o;
      }
    } else {
#pragma unroll
      for (int i = 0; i < rpw / 8; ++i)
        GLOAD_LDS16(Ag + k0 + (size_t)(8 * i) * K, As_w + (8 * i) * BK);
    }
#pragma unroll
    for (int i = 0; i < 4; ++i)
      GLOAD_LDS16(Bg + k0 + (size_t)(8 * i) * K, Bs_w + (8 * i) * BK);
    __syncthreads();
#pragma unroll
    for (int kk = 0; kk < 2; ++kk) {
      f16x8 af[MI], bf[4];
#pragma unroll
      for (int m16 = 0; m16 < MI; ++m16) {
        const int r = moff + m16 * 16 + l16;
        const int ch = (4 * kk + quad) ^ (r & 7);
        af[m16] = *(const f16x8*)&As[r * BK + ch * 8];
      }
#pragma unroll
      for (int n16 = 0; n16 < 4; ++n16) {
        const int r = noff + n16 * 16 + l16;
        const int ch = (4 * kk + quad) ^ (r & 7);
        bf[n16] = *(const f16x8*)&Bs[r * BK + ch * 8];
      }
#pragma unroll
      for (int m16 = 0; m16 < MI; ++m16)
#pragma unroll
        for (int n16 = 0; n16 < 4; ++n16)
          acc[m16][n16] =
              __builtin_amdgcn_mfma_f32_16x16x32_f16(af[m16], bf[n16], acc[m16][n16], 0, 0, 0);
    }
  }

  float bv[4];
#pragma unroll
  for (int n16 = 0; n16 < 4; ++n16)
    bv[n16] = BIAS ? bias[n0 + noff + n16 * 16 + l16] : 0.f;

  if (OUTMODE == 2) {
    const int hblk = (n0 >> 6) + (wave & 1);
    const int which = hblk >> 3, h = hblk & 7;
    f16* dst = (which == 0) ? q_out : (which == 1) ? k_out : v_out;
    // Q gets 1/sqrt(dh) * log2(e) so flash can use exp2 directly.
    const float scale = (which == 0) ? 0.125f * 1.44269504088896340736f : 1.0f;
#pragma unroll
    for (int m16 = 0; m16 < MI; ++m16) {
#pragma unroll
      for (int r = 0; r < 4; ++r) {
        const int m = m0 + moff + m16 * 16 + quad * 4 + r;
        const int b = m >> 11, ns = m & 2047;
        f16* row = dst + ((size_t)(b * 8 + h) * NN + ns) * DH;
#pragma unroll
        for (int n16 = 0; n16 < 4; ++n16) {
          const int d = n16 * 16 + l16;
          row[d] = (f16)((acc[m16][n16][r] + bv[n16]) * scale);
        }
      }
    }
  } else {
#pragma unroll
    for (int m16 = 0; m16 < MI; ++m16) {
#pragma unroll
      for (int r = 0; r < 4; ++r) {
        const size_t row = (size_t)(m0 + moff + m16 * 16 + quad * 4 + r) * N;
#pragma unroll
        for (int n16 = 0; n16 < 4; ++n16) {
          const int col = n0 + noff + n16 * 16 + l16;
          float v = acc[m16][n16][r] + bv[n16];
          if (RELU) v = fmaxf(v, 0.f);
          if (OUTMODE == 0) ((float*)Cout)[row + col] = v;
          else ((f16*)Cout)[row + col] = (f16)v;
        }
      }
    }
  }
}

// ---------------- GCN aggregation v2 (CSR gather, f16x8 per thread) --------

__global__ __launch_bounds__(256) void gcn_aggregate_kernel(const f16* __restrict__ xl,
                                                            const float* __restrict__ dinv,
                                                            const int* __restrict__ rowptr,
                                                            const int* __restrict__ csr_src,
                                                            const float* __restrict__ b_gcn,
                                                            f16* __restrict__ out) {
  __shared__ int s_src[256];
  __shared__ float s_dv[256];
  const int i = blockIdx.x;            // node, shared by all 4 batches
  const int tid = threadIdx.x;
  const float dv_i = dinv[i];
  const int b = tid >> 6;
  const int f = (tid & 63) * 8;
  const f16* xb = xl + (size_t)(b * NN) * HH + f;
  float acc[8];
  {
    const f16x8 self = *(const f16x8*)&xb[(size_t)i * HH];
#pragma unroll
    for (int j = 0; j < 8; ++j) acc[j] = (float)self[j] * dv_i;
  }
  const int beg = rowptr[i], end = rowptr[i + 1];
  for (int c0 = beg; c0 < end; c0 += 256) {
    const int cnt = min(256, end - c0);
    __syncthreads();
    if (tid < cnt) {
      int s = csr_src[c0 + tid];
      s_src[tid] = s;
      s_dv[tid] = dinv[s];
    }
    __syncthreads();
    for (int t = 0; t < cnt; ++t) {
      const f16x8 v = *(const f16x8*)&xb[(size_t)s_src[t] * HH];
      const float w = s_dv[t];
#pragma unroll
      for (int j = 0; j < 8; ++j) acc[j] = fmaf((float)v[j], w, acc[j]);
    }
  }
  const float4 bg0 = *(const float4*)&b_gcn[f];
  const float4 bg1 = *(const float4*)&b_gcn[f + 4];
  f16x8 o;
  o[0] = (f16)(acc[0] * dv_i + bg0.x);
  o[1] = (f16)(acc[1] * dv_i + bg0.y);
  o[2] = (f16)(acc[2] * dv_i + bg0.z);
  o[3] = (f16)(acc[3] * dv_i + bg0.w);
  o[4] = (f16)(acc[4] * dv_i + bg1.x);
  o[5] = (f16)(acc[5] * dv_i + bg1.y);
  o[6] = (f16)(acc[6] * dv_i + bg1.z);
  o[7] = (f16)(acc[7] * dv_i + bg1.w);
  *(f16x8*)&out[((size_t)(b * NN) + i) * HH + f] = o;
}

// ---------------- flash attention v14 (v11 + K-tile 256) ----------------
// Q/K/V: f16 [bh][n][64], Q pre-scaled by 0.125*log2(e) (exp2 softmax).
// Block = 4 waves (256 thr); wave w owns q-16-blocks w and w+4 (2 q-blocks).
// q-tile 128, K-tile 256 (halved barriers vs v11). Grid 512 XCD-swizzled.
// Single-buffered LDS (68 KB -> 2 blocks/CU). l via ones-B MFMA.
// V LDS [64 d][256 kslot], chunk-XOR swizzle ch'=(ch&24)|((ch^fd)&7),
//   fd(d)=(d+(d>>3))&7; sigma slot(k)=(k>>5)*32+((k>>2)&3)*8+((k>>4)&1)*4+(k&3)

__global__ __launch_bounds__(256, 2) void flash_attn_f16_kernel(const f16* __restrict__ Qb,
                                                                const f16* __restrict__ Kb,
                                                                const f16* __restrict__ Vb,
                                                                f16* __restrict__ out) {
  constexpr int KT = 256;   // K-tile
  constexpr int LDK = 72;   // f16 row stride (144 B) -> b128 reads conflict-free
  constexpr int LDV = 256;  // swizzled, no pad
  __shared__ f16 Ks[KT * LDK];    // 36.9 KB
  __shared__ f16 Vt[64 * LDV];    // 32.0 KB
  const int tid = threadIdx.x;
  const int wave = tid >> 6, lane = tid & 63;
  const int quad = lane >> 4, l16 = lane & 15;
  // XCD swizzle: 512 blocks / 8 XCDs = 64 blocks = 4 heads per XCD.
  const int bid = blockIdx.x;
  const int sw = (bid & 7) * 64 + (bid >> 3);
  const int bh = sw >> 4;
  const int n0 = (sw & 15) * 128;
  const int b = bh >> 3, h = bh & 7;
  const f16* kb = Kb + (size_t)bh * NN * DH;
  const f16* vb = Vb + (size_t)bh * NN * DH;

  f16x8 aq[2][2];
#pragma unroll
  for (int g = 0; g < 2; ++g) {
    const f16* qf = Qb + ((size_t)bh * NN + n0 + (wave + 4 * g) * 16 + l16) * DH + quad * 8;
    aq[g][0] = *(const f16x8*)qf;
    aq[g][1] = *(const f16x8*)(qf + 32);
  }

  const f16x8 ones = { (f16)1.f, (f16)1.f, (f16)1.f, (f16)1.f,
                       (f16)1.f, (f16)1.f, (f16)1.f, (f16)1.f };

  f32x4 acc_l[2];
  f32x4 acc_o[2][4];
#pragma unroll
  for (int g = 0; g < 2; ++g) {
    acc_l[g] = (f32x4){0.f, 0.f, 0.f, 0.f};
#pragma unroll
    for (int n16 = 0; n16 < 4; ++n16) acc_o[g][n16] = (f32x4){0.f, 0.f, 0.f, 0.f};
  }

  // staging roles (256 threads): K = 8 b128/thread (rows kr+32i), V = 4 jb
  const int kr = tid >> 3, kc = (tid & 7) * 8;       // rows kr..kr+224
  const int vdg = tid & 15, jbb = tid >> 4;          // jb = jbb + 16*cc, cc<4
  // read-side swizzle keys fd(d) for d = n16*16 + l16
  int fdr[4];
#pragma unroll
  for (int n16 = 0; n16 < 4; ++n16)
    fdr[n16] = (2 * n16 + l16 + (l16 >> 3)) & 7;

  f16x8 kreg[8];
  f16x4 vreg[4][4];

  auto load_tile = [&](int k0) {
#pragma unroll
    for (int i = 0; i < 8; ++i)
      kreg[i] = *(const f16x8*)(kb + (size_t)(k0 + kr + 32 * i) * DH + kc);
#pragma unroll
    for (int cc = 0; cc < 4; ++cc) {
      const int jb = jbb + 16 * cc;
#pragma unroll
      for (int i = 0; i < 4; ++i)
        vreg[cc][i] = *(const f16x4*)(vb + (size_t)(k0 + jb * 4 + i) * DH + vdg * 4);
    }
  };
  auto store_tile = [&]() {
#pragma unroll
    for (int i = 0; i < 8; ++i)
      *(f16x8*)&Ks[(kr + 32 * i) * LDK + kc] = kreg[i];
#pragma unroll
    for (int cc = 0; cc < 4; ++cc) {
      const int jb = jbb + 16 * cc;
      const int vch = (jb >> 3) * 4 + (jb & 3);      // logical 16B chunk 0..31
      const int vrem = ((jb >> 2) & 1) * 4;          // 0 or 4 f16
#pragma unroll
      for (int c = 0; c < 4; ++c) {
        const int d = vdg * 4 + c;
        const int fd = (d + (d >> 3)) & 7;
        const int off = (((vch & 24) | ((vch ^ fd) & 7)) << 3) + vrem;
        f16x4 o = { vreg[cc][0][c], vreg[cc][1][c], vreg[cc][2][c], vreg[cc][3][c] };
        *(f16x4*)&Vt[d * LDV + off] = o;
      }
    }
  };
  auto do_p = [&](int p) {
    f32x4 sA[2][2];  // [g][t]
#pragma unroll
    for (int t = 0; t < 2; ++t) {
      const f16x8 ak0 = *(const f16x8*)&Ks[(p * 32 + t * 16 + l16) * LDK + quad * 8];
      const f16x8 ak1 = *(const f16x8*)&Ks[(p * 32 + t * 16 + l16) * LDK + quad * 8 + 32];
#pragma unroll
      for (int g = 0; g < 2; ++g) {
        f32x4 s = {0.f, 0.f, 0.f, 0.f};
        s = __builtin_amdgcn_mfma_f32_16x16x32_f16(ak0, aq[g][0], s, 0, 0, 0);
        s = __builtin_amdgcn_mfma_f32_16x16x32_f16(ak1, aq[g][1], s, 0, 0, 0);
        sA[g][t] = s;
      }
    }
    f16x8 bvv[4];
    const int chp = p * 4 + quad;     // logical 16B chunk 0..31
#pragma unroll
    for (int n16 = 0; n16 < 4; ++n16) {
      const int off = ((chp & 24) | ((chp ^ fdr[n16]) & 7)) << 3;
      bvv[n16] = *(const f16x8*)&Vt[(n16 * 16 + l16) * LDV + off];
    }
#pragma unroll
    for (int g = 0; g < 2; ++g) {
      union { f16x8 v; f16x2 hh[4]; } ap;
#pragma unroll
      for (int t = 0; t < 2; ++t)
#pragma unroll
        for (int rr = 0; rr < 2; ++rr) {
          const float e0 = fast_exp2(sA[g][t][rr * 2]);
          const float e1 = fast_exp2(sA[g][t][rr * 2 + 1]);
          ap.hh[t * 2 + rr] = cvt_pk_f16(e0, e1);
        }
      // l via ones-B MFMA: C[q][*] = sum_k P[q][k]; lands in acc_o layout.
      acc_l[g] = __builtin_amdgcn_mfma_f32_16x16x32_f16(ap.v, ones, acc_l[g], 0, 0, 0);
#pragma unroll
      for (int n16 = 0; n16 < 4; ++n16)
        acc_o[g][n16] = __builtin_amdgcn_mfma_f32_16x16x32_f16(ap.v, bvv[n16], acc_o[g][n16], 0, 0, 0);
    }
  };

  // prologue: tile 0 staged
  load_tile(0);
  store_tile();
  __syncthreads();
  for (int kt = 0; kt < NN / KT; ++kt) {
    const bool pf = (kt + 1) < (NN / KT);
    if (pf) load_tile((kt + 1) * KT);    // global loads fly under compute
    __builtin_amdgcn_s_setprio(1);
#pragma unroll
    for (int p = 0; p < 8; ++p) do_p(p);
    __builtin_amdgcn_s_setprio(0);
    __syncthreads();                      // all reads of this tile done
    if (pf) {
      store_tile();                       // vmcnt wait covered by compute
      __syncthreads();                    // stores visible
    }
  }

  // epilogue: l is in-lane (acc_l[g][r] = l for q-row quad*4+r); no shuffles.
#pragma unroll
  for (int g = 0; g < 2; ++g) {
    f16* obase = out + ((size_t)b * NN + n0 + (wave + 4 * g) * 16) * HH + h * DH;
#pragma unroll
    for (int r = 0; r < 4; ++r) {
      const float inv = 1.0f / acc_l[g][r];
#pragma unroll
      for (int n16 = 0; n16 < 4; ++n16)
        obase[(size_t)(quad * 4 + r) * HH + n16 * 16 + l16] = (f16)(acc_o[g][n16][r] * inv);
    }
  }
}

// ---------------------------------------------------------------------------

extern "C" void kernel_launch(void* const* d_in, const int* in_sizes, int n_in,
                              void* d_out, int out_size, void* d_ws, size_t ws_size,
                              hipStream_t stream) {
  const float* x     = (const float*)d_in[0];
  const int*   ei    = (const int*)d_in[1];
  const float* W_gcn = (const float*)d_in[2];
  const float* b_gcn = (const float*)d_in[3];
  const float* wi    = (const float*)d_in[4];
  const float* bi    = (const float*)d_in[5];
  const float* wo    = (const float*)d_in[6];
  const float* bo    = (const float*)d_in[7];
  const float* fcw   = (const float*)d_in[8];
  const float* fcb   = (const float*)d_in[9];
  float* out = (float*)d_out;
  const int E = in_sizes[1] / 2;  // 65536
  const int M = 4 * NN;           // 8192 rows

  char* wsb = (char*)d_ws;
  const size_t MB = 1u << 20;
  f16* xl16   = (f16*)(wsb + 4 * MB);         // 8 MB
  f16* hb16   = (f16*)(wsb + 12 * MB);        // 8 MB
  f16* Qb     = (f16*)(wsb + 20 * MB);        // 8 MB
  f16* Kb     = (f16*)(wsb + 28 * MB);        // 8 MB
  f16* Vb     = (f16*)(wsb + 36 * MB);        // 8 MB
  f16* attn16 = (f16*)(wsb + 44 * MB);        // 8 MB
  f16* proj16 = (f16*)(wsb + 52 * MB);        // 8 MB
  f16* wi16   = (f16*)(wsb + 60 * MB);        // 1.5 MB  [1536,512] (n,k)
  f16* wo16   = (f16*)(wsb + 62 * MB);        // 0.5 MB  [512,512]  (n,k)
  f16* wg16t  = (f16*)(wsb + 63 * MB);        // 0.25 MB [512,256]  (n,k)
  f16* fcw16t = (f16*)(wsb + 64 * MB);        // 0.25 MB [256,512]  (n,k)
  float* deg  = (float*)(wsb + 65 * MB);
  float* dinv = deg + NN;
  int* rowptr = (int*)(dinv + NN);
  int* cursor = rowptr + 2080;
  int* csr    = cursor + NN;                  // E ints

  // fused prep: converts + transposes + deg/cursor init
  prep_all_kernel<<<1281, 256, 0, stream>>>(wi, wo, W_gcn, fcw, wi16, wo16,
                                            wg16t, fcw16t, deg, cursor);

  // CSR build
  count_deg_kernel<<<(E + 255) / 256, 256, 0, stream>>>(ei, E, deg);
  build_rowptr_kernel<<<1, 1024, 0, stream>>>(deg, dinv, rowptr);
  fill_csr_kernel<<<(E + 255) / 256, 256, 0, stream>>>(ei, E, rowptr, cursor, csr);

  // xl = x @ W_gcn -> f16 (A staged f32->f16 in-kernel)  [8192,512]
  mfma_gemm_kernel<1, false, false, true><<<dim3(4, 64), 256, 0, stream>>>(
      x, wg16t, nullptr, xl16, M, 512, 256, nullptr, nullptr, nullptr);
  // h = GCN aggregate + b_gcn -> f16   [8192,512]
  gcn_aggregate_kernel<<<NN, 256, 0, stream>>>(xl16, dinv, rowptr, csr, b_gcn, hb16);
  // qkv = h @ wi^T + bi -> Q/K/V split f16 [bh][n][64], Q scaled by .125*log2e
  mfma_gemm_kernel<2, true, false, false><<<dim3(12, 64), 256, 0, stream>>>(
      hb16, wi16, bi, nullptr, M, 1536, 512, Qb, Kb, Vb);
  // attention -> attn16                [8192,512]
  flash_attn_f16_kernel<<<512, 256, 0, stream>>>(Qb, Kb, Vb, attn16);
  // proj = relu(attn @ wo^T + bo) -> f16
  mfma_gemm_kernel<1, true, true, false><<<dim3(4, 64), 256, 0, stream>>>(
      attn16, wo16, bo, proj16, M, 512, 512, nullptr, nullptr, nullptr);
  // out = proj @ fc_w + fc_b -> f32    [8192,256]  (MT=64: 256 blocks)
  mfma_gemm_kernel<0, true, false, false, 64><<<dim3(2, 128), 256, 0, stream>>>(
      proj16, fcw16t, fcb, out, M, 256, 512, nullptr, nullptr, nullptr);
}

// Round 18
// 220.744 us; speedup vs baseline: 1.0715x; 1.0715x over previous
//
#include <hip/hip_runtime.h>
#include <hip/hip_bf16.h>

// ---------------------------------------------------------------------------
// GCNWithSelfAttention: GCNConv -> MHA(8 heads) -> ReLU -> Linear
// B=4, N=2048, Din=256, H=512, nh=8, dh=64, E=65536, Dout=256.
// Flash = v11 verbatim (best measured 45.8us; K-tile 256 regressed r16:
// +32 VGPR prefetch-hold > barrier savings). GEMMs: BK=64 + T2 both-sides
// XOR swizzle (r15: -5.5us) + XCD-aware 1-D grid swizzle (T1): consecutive
// n-blocks (sharing B panel) land on one XCD -> panel L2-resident.
// (Resubmission — round-17 broker timeout, kernel never ran.)
// ---------------------------------------------------------------------------

#define NN 2048
#define HH 512
#define NHEAD 8
#define DH 64

typedef _Float16 f16;
typedef __attribute__((ext_vector_type(2))) _Float16 f16x2;
typedef __attribute__((ext_vector_type(4))) _Float16 f16x4;
typedef __attribute__((ext_vector_type(8))) _Float16 f16x8;
typedef __attribute__((ext_vector_type(4))) float f32x4;

#define GLOAD_LDS16(g, l)                                              \
  __builtin_amdgcn_global_load_lds(                                    \
      (const __attribute__((address_space(1))) void*)(g),              \
      (__attribute__((address_space(3))) void*)(l), 16, 0, 0)

__device__ __forceinline__ float fast_exp2(float x) {
#if __has_builtin(__builtin_amdgcn_exp2f)
  return __builtin_amdgcn_exp2f(x);
#else
  return exp2f(x);
#endif
}

__device__ __forceinline__ f16x2 cvt_pk_f16(float a, float b) {
#if __has_builtin(__builtin_amdgcn_cvt_pkrtz)
  return __builtin_bit_cast(f16x2, __builtin_amdgcn_cvt_pkrtz(a, b));
#else
  f16x2 r = { (f16)a, (f16)b };
  return r;
#endif
}

// ---------------- fused prep: converts + transposes + deg/cursor init ------

__global__ __launch_bounds__(256) void prep_all_kernel(const float* __restrict__ wi,
                                                       const float* __restrict__ wo,
                                                       const float* __restrict__ wg,
                                                       const float* __restrict__ fcw,
                                                       f16* __restrict__ wi16,
                                                       f16* __restrict__ wo16,
                                                       f16* __restrict__ wg16t,
                                                       f16* __restrict__ fcw16t,
                                                       float* __restrict__ deg,
                                                       int* __restrict__ cursor) {
  __shared__ float tbuf[32][33];
  const int bid = blockIdx.x, t = threadIdx.x;
  if (bid < 768) {                       // wi: 1536*512 f32 = 196608 float4
    const int i = bid * 256 + t;
    const float4 v = ((const float4*)wi)[i];
    f16x4 o = { (f16)v.x, (f16)v.y, (f16)v.z, (f16)v.w };
    ((f16x4*)wi16)[i] = o;
  } else if (bid < 1024) {               // wo: 512*512 f32 = 65536 float4
    const int i = (bid - 768) * 256 + t;
    const float4 v = ((const float4*)wo)[i];
    f16x4 o = { (f16)v.x, (f16)v.y, (f16)v.z, (f16)v.w };
    ((f16x4*)wo16)[i] = o;
  } else if (bid == 1024) {              // deg/cursor init (count_deg adds)
    for (int i = t; i < NN; i += 256) { deg[i] = 0.0f; cursor[i] = 0; }
  } else {                               // transpose-converts
    const int id = bid - 1025;
    const float* in;
    f16* outp;
    int R, C, bx, by;
    if (id < 128) { in = wg;  outp = wg16t;  R = 256; C = 512;
                    bx = id & 15; by = id >> 4; }
    else { int id2 = id - 128; in = fcw; outp = fcw16t; R = 512; C = 256;
           bx = id2 & 7; by = id2 >> 3; }
    const int c0 = bx * 32, r0 = by * 32;
    const int tx = t & 31, ty = t >> 5;
#pragma unroll
    for (int i = 0; i < 32; i += 8) tbuf[ty + i][tx] = in[(size_t)(r0 + ty + i) * C + c0 + tx];
    __syncthreads();
#pragma unroll
    for (int i = 0; i < 32; i += 8)
      outp[(size_t)(c0 + ty + i) * R + r0 + tx] = (f16)tbuf[tx][ty + i];
  }
}

// ---------------- degree / CSR build ----------------

__global__ __launch_bounds__(256) void count_deg_kernel(const int* __restrict__ ei, int E,
                                                        float* __restrict__ deg) {
  int e = blockIdx.x * 256 + threadIdx.x;
  if (e < E) atomicAdd(&deg[ei[E + e]], 1.0f);  // dst row
}

__global__ __launch_bounds__(1024) void build_rowptr_kernel(const float* __restrict__ deg,
                                                            float* __restrict__ dinv,
                                                            int* __restrict__ rowptr) {
  __shared__ int a[NN];
  __shared__ int bbuf[NN];
  const int t = threadIdx.x;
  for (int i = t; i < NN; i += 1024) {
    float dg = deg[i];               // edge count (self-loop NOT included)
    a[i] = (int)dg;
    dinv[i] = rsqrtf(dg + 1.0f);     // degree incl. self-loop
  }
  __syncthreads();
  int* src = a;
  int* dst = bbuf;
  for (int off = 1; off < NN; off <<= 1) {
    for (int i = t; i < NN; i += 1024) {
      int v = src[i];
      if (i >= off) v += src[i - off];
      dst[i] = v;
    }
    __syncthreads();
    int* tmp = src; src = dst; dst = tmp;
  }
  for (int i = t; i < NN; i += 1024) rowptr[i + 1] = src[i];
  if (t == 0) rowptr[0] = 0;
}

__global__ __launch_bounds__(256) void fill_csr_kernel(const int* __restrict__ ei, int E,
                                                       const int* __restrict__ rowptr,
                                                       int* __restrict__ cursor,
                                                       int* __restrict__ csr_src) {
  int e = blockIdx.x * 256 + threadIdx.x;
  if (e < E) {
    int s = ei[e];
    int d = ei[E + e];
    int pos = atomicAdd(&cursor[d], 1);
    csr_src[rowptr[d] + pos] = s;
  }
}

// ---------------- f16 MFMA GEMM: C[M,N] = A[M,K] * Bt[N,K]^T (+bias)(+relu) -
// MTxN128 tile, BK=64, 256 thr = 4 waves; MT=128: wave=64x64 (4x4 mfma),
// MT=64: wave=32x64 (2x4). OUTMODE: 0 f32 [M,N]; 1 f16 [M,N]; 2 qkv split.
// AF32: A is f32, converted during staging.
// 1-D grid, XCD swizzle (T1): swz=(bid&7)*(total/8)+(bid>>3); n fastest so
// each XCD's contiguous chunk shares B panels (L2-resident).
// LDS XOR swizzle (T2, both-sides): chunk c of row r at c^(r&7); staging
// pre-swizzles the GLOBAL source col (rule 21); reads apply the same XOR.

template <int OUTMODE, bool BIAS, bool RELU, bool AF32, int MT = 128>
__global__ __launch_bounds__(256) void mfma_gemm_kernel(
    const void* __restrict__ Ap, const f16* __restrict__ Bt,
    const float* __restrict__ bias, void* __restrict__ Cout,
    int M, int N, int K,
    f16* __restrict__ q_out, f16* __restrict__ k_out, f16* __restrict__ v_out) {
  constexpr int MI = MT / 32;  // 16-row blocks per wave in M
  constexpr int BK = 64;
  __shared__ f16 As[MT * BK];   // 16 KB (MT=128) / 8 KB (MT=64)
  __shared__ f16 Bs[128 * BK];  // 16 KB
  const int tid = threadIdx.x;
  const int wave = tid >> 6, lane = tid & 63;
  const int quad = lane >> 4, l16 = lane & 15;
  // XCD-aware 1-D grid swizzle (total % 8 == 0 for all our grids)
  const int bidr = blockIdx.x;
  const int cpx = gridDim.x >> 3;
  const int swz = (bidr & 7) * cpx + (bidr >> 3);
  const int nbx = N >> 7;
  const int m0 = (swz / nbx) * MT, n0 = (swz % nbx) * 128;
  const int moff = (wave >> 1) * (MI * 16), noff = (wave & 1) * 64;

  f32x4 acc[MI][4];
#pragma unroll
  for (int i = 0; i < MI; ++i)
#pragma unroll
    for (int j = 0; j < 4; ++j) acc[i][j] = (f32x4){0.f, 0.f, 0.f, 0.f};

  const int rpw = MT / 4;       // A rows staged per wave
  const int srow8 = lane >> 3;  // row within an 8-row staging group
  // pre-swizzled global col chunk: LDS chunk (lane&7) holds global chunk
  // (lane&7)^(row&7); row&7 == srow8 for every staging group.
  const int kchsw = (((lane & 7) ^ srow8) * 8);
  const f16* Ag = (const f16*)Ap + (size_t)(m0 + rpw * wave + srow8) * K + kchsw;
  const float* Ag32 = (const float*)Ap + (size_t)(m0 + rpw * wave + srow8) * K + kchsw;
  const f16* Bg = Bt + (size_t)(n0 + 32 * wave + srow8) * K + kchsw;
  f16* As_w = &As[(rpw * wave) * BK];
  f16* Bs_w = &Bs[(32 * wave) * BK];

  for (int k0 = 0; k0 < K; k0 += BK) {
    __syncthreads();
    if (AF32) {
#pragma unroll
      for (int i = 0; i < rpw / 8; ++i) {
        const float* g = Ag32 + k0 + (size_t)(8 * i) * K;
        const float4 u0 = *(const float4*)g;
        const float4 u1 = *(const float4*)(g + 4);
        f16x8 o = { (f16)u0.x, (f16)u0.y, (f16)u0.z, (f16)u0.w,
                    (f16)u1.x, (f16)u1.y, (f16)u1.z, (f16)u1.w };
        *(f16x8*)&As[(rpw * wave + 8 * i + srow8) * BK + (lane & 7) * 8] = o;
      }
    } else {
#pragma unroll
      for (int i = 0; i < rpw / 8; ++i)
        GLOAD_LDS16(Ag + k0 + (size_t)(8 * i) * K, As_w + (8 * i) * BK);
    }
#pragma unroll
    for (int i = 0; i < 4; ++i)
      GLOAD_LDS16(Bg + k0 + (size_t)(8 * i) * K, Bs_w + (8 * i) * BK);
    __syncthreads();
#pragma unroll
    for (int kk = 0; kk < 2; ++kk) {
      f16x8 af[MI], bf[4];
#pragma unroll
      for (int m16 = 0; m16 < MI; ++m16) {
        const int r = moff + m16 * 16 + l16;
        const int ch = (4 * kk + quad) ^ (r & 7);
        af[m16] = *(const f16x8*)&As[r * BK + ch * 8];
      }
#pragma unroll
      for (int n16 = 0; n16 < 4; ++n16) {
        const int r = noff + n16 * 16 + l16;
        const int ch = (4 * kk + quad) ^ (r & 7);
        bf[n16] = *(const f16x8*)&Bs[r * BK + ch * 8];
      }
#pragma unroll
      for (int m16 = 0; m16 < MI; ++m16)
#pragma unroll
        for (int n16 = 0; n16 < 4; ++n16)
          acc[m16][n16] =
              __builtin_amdgcn_mfma_f32_16x16x32_f16(af[m16], bf[n16], acc[m16][n16], 0, 0, 0);
    }
  }

  float bv[4];
#pragma unroll
  for (int n16 = 0; n16 < 4; ++n16)
    bv[n16] = BIAS ? bias[n0 + noff + n16 * 16 + l16] : 0.f;

  if (OUTMODE == 2) {
    const int hblk = (n0 >> 6) + (wave & 1);
    const int which = hblk >> 3, h = hblk & 7;
    f16* dst = (which == 0) ? q_out : (which == 1) ? k_out : v_out;
    // Q gets 1/sqrt(dh) * log2(e) so flash can use exp2 directly.
    const float scale = (which == 0) ? 0.125f * 1.44269504088896340736f : 1.0f;
#pragma unroll
    for (int m16 = 0; m16 < MI; ++m16) {
#pragma unroll
      for (int r = 0; r < 4; ++r) {
        const int m = m0 + moff + m16 * 16 + quad * 4 + r;
        const int b = m >> 11, ns = m & 2047;
        f16* row = dst + ((size_t)(b * 8 + h) * NN + ns) * DH;
#pragma unroll
        for (int n16 = 0; n16 < 4; ++n16) {
          const int d = n16 * 16 + l16;
          row[d] = (f16)((acc[m16][n16][r] + bv[n16]) * scale);
        }
      }
    }
  } else {
#pragma unroll
    for (int m16 = 0; m16 < MI; ++m16) {
#pragma unroll
      for (int r = 0; r < 4; ++r) {
        const size_t row = (size_t)(m0 + moff + m16 * 16 + quad * 4 + r) * N;
#pragma unroll
        for (int n16 = 0; n16 < 4; ++n16) {
          const int col = n0 + noff + n16 * 16 + l16;
          float v = acc[m16][n16][r] + bv[n16];
          if (RELU) v = fmaxf(v, 0.f);
          if (OUTMODE == 0) ((float*)Cout)[row + col] = v;
          else ((f16*)Cout)[row + col] = (f16)v;
        }
      }
    }
  }
}

// ---------------- GCN aggregation v2 (CSR gather, f16x8 per thread) --------

__global__ __launch_bounds__(256) void gcn_aggregate_kernel(const f16* __restrict__ xl,
                                                            const float* __restrict__ dinv,
                                                            const int* __restrict__ rowptr,
                                                            const int* __restrict__ csr_src,
                                                            const float* __restrict__ b_gcn,
                                                            f16* __restrict__ out) {
  __shared__ int s_src[256];
  __shared__ float s_dv[256];
  const int i = blockIdx.x;            // node, shared by all 4 batches
  const int tid = threadIdx.x;
  const float dv_i = dinv[i];
  const int b = tid >> 6;
  const int f = (tid & 63) * 8;
  const f16* xb = xl + (size_t)(b * NN) * HH + f;
  float acc[8];
  {
    const f16x8 self = *(const f16x8*)&xb[(size_t)i * HH];
#pragma unroll
    for (int j = 0; j < 8; ++j) acc[j] = (float)self[j] * dv_i;
  }
  const int beg = rowptr[i], end = rowptr[i + 1];
  for (int c0 = beg; c0 < end; c0 += 256) {
    const int cnt = min(256, end - c0);
    __syncthreads();
    if (tid < cnt) {
      int s = csr_src[c0 + tid];
      s_src[tid] = s;
      s_dv[tid] = dinv[s];
    }
    __syncthreads();
    for (int t = 0; t < cnt; ++t) {
      const f16x8 v = *(const f16x8*)&xb[(size_t)s_src[t] * HH];
      const float w = s_dv[t];
#pragma unroll
      for (int j = 0; j < 8; ++j) acc[j] = fmaf((float)v[j], w, acc[j]);
    }
  }
  const float4 bg0 = *(const float4*)&b_gcn[f];
  const float4 bg1 = *(const float4*)&b_gcn[f + 4];
  f16x8 o;
  o[0] = (f16)(acc[0] * dv_i + bg0.x);
  o[1] = (f16)(acc[1] * dv_i + bg0.y);
  o[2] = (f16)(acc[2] * dv_i + bg0.z);
  o[3] = (f16)(acc[3] * dv_i + bg0.w);
  o[4] = (f16)(acc[4] * dv_i + bg1.x);
  o[5] = (f16)(acc[5] * dv_i + bg1.y);
  o[6] = (f16)(acc[6] * dv_i + bg1.z);
  o[7] = (f16)(acc[7] * dv_i + bg1.w);
  *(f16x8*)&out[((size_t)(b * NN) + i) * HH + f] = o;
}

// ---------------- flash attention v11 (verbatim best: 45.8us) ----------------
// Q/K/V: f16 [bh][n][64], Q pre-scaled by 0.125*log2(e) (exp2 softmax).
// Block = 4 waves (256 thr); wave w owns q-16-blocks w and w+4 (2 q-blocks,
// K/V LDS reads amortized 2x). q-tile 128, K-tile 128. Grid 512 XCD-swizzled.
// Single-buffered LDS (34.4 KB). l computed via ones-B MFMA: acc_l[g][r] =
// l for q-row quad*4+r (in acc_o layout) -> no VALU sum, no epilogue shuffle.
// V LDS [64 d][128 kslot], chunk-XOR swizzle ch'=(ch&8)|((ch^fd)&7),
//   fd(d)=(d+(d>>3))&7; sigma slot(k)=(k>>5)*32+((k>>2)&3)*8+((k>>4)&1)*4+(k&3)

__global__ __launch_bounds__(256, 2) void flash_attn_f16_kernel(const f16* __restrict__ Qb,
                                                                const f16* __restrict__ Kb,
                                                                const f16* __restrict__ Vb,
                                                                f16* __restrict__ out) {
  constexpr int LDK = 72;   // f16 row stride (144 B) -> b128 reads conflict-free
  constexpr int LDV = 128;  // swizzled, no pad
  __shared__ f16 Ks[128 * LDK];   // 18.4 KB
  __shared__ f16 Vt[64 * LDV];    // 16.0 KB
  const int tid = threadIdx.x;
  const int wave = tid >> 6, lane = tid & 63;
  const int quad = lane >> 4, l16 = lane & 15;
  // XCD swizzle: 512 blocks / 8 XCDs = 64 blocks = 4 heads per XCD.
  const int bid = blockIdx.x;
  const int sw = (bid & 7) * 64 + (bid >> 3);
  const int bh = sw >> 4;
  const int n0 = (sw & 15) * 128;
  const int b = bh >> 3, h = bh & 7;
  const f16* kb = Kb + (size_t)bh * NN * DH;
  const f16* vb = Vb + (size_t)bh * NN * DH;

  f16x8 aq[2][2];
#pragma unroll
  for (int g = 0; g < 2; ++g) {
    const f16* qf = Qb + ((size_t)bh * NN + n0 + (wave + 4 * g) * 16 + l16) * DH + quad * 8;
    aq[g][0] = *(const f16x8*)qf;
    aq[g][1] = *(const f16x8*)(qf + 32);
  }

  const f16x8 ones = { (f16)1.f, (f16)1.f, (f16)1.f, (f16)1.f,
                       (f16)1.f, (f16)1.f, (f16)1.f, (f16)1.f };

  f32x4 acc_l[2];
  f32x4 acc_o[2][4];
#pragma unroll
  for (int g = 0; g < 2; ++g) {
    acc_l[g] = (f32x4){0.f, 0.f, 0.f, 0.f};
#pragma unroll
    for (int n16 = 0; n16 < 4; ++n16) acc_o[g][n16] = (f32x4){0.f, 0.f, 0.f, 0.f};
  }

  // staging roles (256 threads): K = 4 b128/thread (rows kr+32i), V = 2 jb
  const int kr = tid >> 3, kc = (tid & 7) * 8;       // rows kr..kr+96
  const int vdg = tid & 15, jbb = tid >> 4;          // jb = jbb, jbb+16
  // read-side swizzle keys fd(d) for d = n16*16 + l16
  int fdr[4];
#pragma unroll
  for (int n16 = 0; n16 < 4; ++n16)
    fdr[n16] = (2 * n16 + l16 + (l16 >> 3)) & 7;

  f16x8 kreg[4];
  f16x4 vreg[2][4];

  auto load_tile = [&](int k0) {
#pragma unroll
    for (int i = 0; i < 4; ++i)
      kreg[i] = *(const f16x8*)(kb + (size_t)(k0 + kr + 32 * i) * DH + kc);
#pragma unroll
    for (int cc = 0; cc < 2; ++cc) {
      const int jb = jbb + 16 * cc;
#pragma unroll
      for (int i = 0; i < 4; ++i)
        vreg[cc][i] = *(const f16x4*)(vb + (size_t)(k0 + jb * 4 + i) * DH + vdg * 4);
    }
  };
  auto store_tile = [&]() {
#pragma unroll
    for (int i = 0; i < 4; ++i)
      *(f16x8*)&Ks[(kr + 32 * i) * LDK + kc] = kreg[i];
#pragma unroll
    for (int cc = 0; cc < 2; ++cc) {
      const int jb = jbb + 16 * cc;
      const int vch = (jb >> 3) * 4 + (jb & 3);      // logical 16B chunk
      const int vrem = ((jb >> 2) & 1) * 4;          // 0 or 4 f16
#pragma unroll
      for (int c = 0; c < 4; ++c) {
        const int d = vdg * 4 + c;
        const int fd = (d + (d >> 3)) & 7;
        const int off = (((vch & 8) | ((vch ^ fd) & 7)) << 3) + vrem;
        f16x4 o = { vreg[cc][0][c], vreg[cc][1][c], vreg[cc][2][c], vreg[cc][3][c] };
        *(f16x4*)&Vt[d * LDV + off] = o;
      }
    }
  };
  auto do_p = [&](int p) {
    f32x4 sA[2][2];  // [g][t]
#pragma unroll
    for (int t = 0; t < 2; ++t) {
      const f16x8 ak0 = *(const f16x8*)&Ks[(p * 32 + t * 16 + l16) * LDK + quad * 8];
      const f16x8 ak1 = *(const f16x8*)&Ks[(p * 32 + t * 16 + l16) * LDK + quad * 8 + 32];
#pragma unroll
      for (int g = 0; g < 2; ++g) {
        f32x4 s = {0.f, 0.f, 0.f, 0.f};
        s = __builtin_amdgcn_mfma_f32_16x16x32_f16(ak0, aq[g][0], s, 0, 0, 0);
        s = __builtin_amdgcn_mfma_f32_16x16x32_f16(ak1, aq[g][1], s, 0, 0, 0);
        sA[g][t] = s;
      }
    }
    f16x8 bvv[4];
    const int chp = p * 4 + quad;     // logical 16B chunk of this lane's read
#pragma unroll
    for (int n16 = 0; n16 < 4; ++n16) {
      const int off = ((chp & 8) | ((chp ^ fdr[n16]) & 7)) << 3;
      bvv[n16] = *(const f16x8*)&Vt[(n16 * 16 + l16) * LDV + off];
    }
#pragma unroll
    for (int g = 0; g < 2; ++g) {
      union { f16x8 v; f16x2 hh[4]; } ap;
#pragma unroll
      for (int t = 0; t < 2; ++t)
#pragma unroll
        for (int rr = 0; rr < 2; ++rr) {
          const float e0 = fast_exp2(sA[g][t][rr * 2]);
          const float e1 = fast_exp2(sA[g][t][rr * 2 + 1]);
          ap.hh[t * 2 + rr] = cvt_pk_f16(e0, e1);
        }
      // l via ones-B MFMA: C[q][*] = sum_k P[q][k]; lands in acc_o layout.
      acc_l[g] = __builtin_amdgcn_mfma_f32_16x16x32_f16(ap.v, ones, acc_l[g], 0, 0, 0);
#pragma unroll
      for (int n16 = 0; n16 < 4; ++n16)
        acc_o[g][n16] = __builtin_amdgcn_mfma_f32_16x16x32_f16(ap.v, bvv[n16], acc_o[g][n16], 0, 0, 0);
    }
  };

  // prologue: tile 0 staged
  load_tile(0);
  store_tile();
  __syncthreads();
  for (int kt = 0; kt < NN / 128; ++kt) {
    const bool pf = (kt + 1) < (NN / 128);
    if (pf) load_tile((kt + 1) * 128);   // global loads fly under compute
    __builtin_amdgcn_s_setprio(1);
    do_p(0);
    do_p(1);
    do_p(2);
    do_p(3);
    __builtin_amdgcn_s_setprio(0);
    __syncthreads();                      // all reads of this tile done
    if (pf) {
      store_tile();                       // vmcnt wait covered by compute
      __syncthreads();                    // stores visible
    }
  }

  // epilogue: l is in-lane (acc_l[g][r] = l for q-row quad*4+r); no shuffles.
#pragma unroll
  for (int g = 0; g < 2; ++g) {
    f16* obase = out + ((size_t)b * NN + n0 + (wave + 4 * g) * 16) * HH + h * DH;
#pragma unroll
    for (int r = 0; r < 4; ++r) {
      const float inv = 1.0f / acc_l[g][r];
#pragma unroll
      for (int n16 = 0; n16 < 4; ++n16)
        obase[(size_t)(quad * 4 + r) * HH + n16 * 16 + l16] = (f16)(acc_o[g][n16][r] * inv);
    }
  }
}

// ---------------------------------------------------------------------------

extern "C" void kernel_launch(void* const* d_in, const int* in_sizes, int n_in,
                              void* d_out, int out_size, void* d_ws, size_t ws_size,
                              hipStream_t stream) {
  const float* x     = (const float*)d_in[0];
  const int*   ei    = (const int*)d_in[1];
  const float* W_gcn = (const float*)d_in[2];
  const float* b_gcn = (const float*)d_in[3];
  const float* wi    = (const float*)d_in[4];
  const float* bi    = (const float*)d_in[5];
  const float* wo    = (const float*)d_in[6];
  const float* bo    = (const float*)d_in[7];
  const float* fcw   = (const float*)d_in[8];
  const float* fcb   = (const float*)d_in[9];
  float* out = (float*)d_out;
  const int E = in_sizes[1] / 2;  // 65536
  const int M = 4 * NN;           // 8192 rows

  char* wsb = (char*)d_ws;
  const size_t MB = 1u << 20;
  f16* xl16   = (f16*)(wsb + 4 * MB);         // 8 MB
  f16* hb16   = (f16*)(wsb + 12 * MB);        // 8 MB
  f16* Qb     = (f16*)(wsb + 20 * MB);        // 8 MB
  f16* Kb     = (f16*)(wsb + 28 * MB);        // 8 MB
  f16* Vb     = (f16*)(wsb + 36 * MB);        // 8 MB
  f16* attn16 = (f16*)(wsb + 44 * MB);        // 8 MB
  f16* proj16 = (f16*)(wsb + 52 * MB);        // 8 MB
  f16* wi16   = (f16*)(wsb + 60 * MB);        // 1.5 MB  [1536,512] (n,k)
  f16* wo16   = (f16*)(wsb + 62 * MB);        // 0.5 MB  [512,512]  (n,k)
  f16* wg16t  = (f16*)(wsb + 63 * MB);        // 0.25 MB [512,256]  (n,k)
  f16* fcw16t = (f16*)(wsb + 64 * MB);        // 0.25 MB [256,512]  (n,k)
  float* deg  = (float*)(wsb + 65 * MB);
  float* dinv = deg + NN;
  int* rowptr = (int*)(dinv + NN);
  int* cursor = rowptr + 2080;
  int* csr    = cursor + NN;                  // E ints

  // fused prep: converts + transposes + deg/cursor init
  prep_all_kernel<<<1281, 256, 0, stream>>>(wi, wo, W_gcn, fcw, wi16, wo16,
                                            wg16t, fcw16t, deg, cursor);

  // CSR build
  count_deg_kernel<<<(E + 255) / 256, 256, 0, stream>>>(ei, E, deg);
  build_rowptr_kernel<<<1, 1024, 0, stream>>>(deg, dinv, rowptr);
  fill_csr_kernel<<<(E + 255) / 256, 256, 0, stream>>>(ei, E, rowptr, cursor, csr);

  // xl = x @ W_gcn -> f16 (A staged f32->f16 in-kernel)  [8192,512]  grid 256
  mfma_gemm_kernel<1, false, false, true><<<256, 256, 0, stream>>>(
      x, wg16t, nullptr, xl16, M, 512, 256, nullptr, nullptr, nullptr);
  // h = GCN aggregate + b_gcn -> f16   [8192,512]
  gcn_aggregate_kernel<<<NN, 256, 0, stream>>>(xl16, dinv, rowptr, csr, b_gcn, hb16);
  // qkv = h @ wi^T + bi -> Q/K/V split f16 [bh][n][64]  grid 768
  mfma_gemm_kernel<2, true, false, false><<<768, 256, 0, stream>>>(
      hb16, wi16, bi, nullptr, M, 1536, 512, Qb, Kb, Vb);
  // attention -> attn16                [8192,512]
  flash_attn_f16_kernel<<<512, 256, 0, stream>>>(Qb, Kb, Vb, attn16);
  // proj = relu(attn @ wo^T + bo) -> f16  grid 256
  mfma_gemm_kernel<1, true, true, false><<<256, 256, 0, stream>>>(
      attn16, wo16, bo, proj16, M, 512, 512, nullptr, nullptr, nullptr);
  // out = proj @ fc_w + fc_b -> f32    [8192,256]  (MT=64) grid 256
  mfma_gemm_kernel<0, true, false, false, 64><<<256, 256, 0, stream>>>(
      proj16, fcw16t, fcb, out, M, 256, 512, nullptr, nullptr, nullptr);
}